// Round 6
// baseline (204.029 us; speedup 1.0000x reference)
//
#include <hip/hip_runtime.h>
#include <hip/hip_fp16.h>

#define TOKENS 8192
#define IN_F   4096
#define OUT_F  4096
#define NK64   (IN_F / 64)   // 64 K-steps of 64 bytes

#define REG    16384         // one matrix region: 16 frags x 1 KB (frag-linear layout)
#define BUFSZ  (2 * REG)     // A + B = 32 KiB per ring buffer
typedef __attribute__((ext_vector_type(4))) int i32x4;

// ---------------- prep: pack int32->int8 (x and w) + bias echo ----------------
__global__ void prep_kernel(const int4* __restrict__ xs, const int4* __restrict__ ws,
                            const float* __restrict__ bias,
                            int4* __restrict__ xp, int4* __restrict__ wp,
                            float* __restrict__ out_tail) {
    const int NX = TOKENS * IN_F / 16;
    const int NW = OUT_F * IN_F / 16;
    const int gid = blockIdx.x * blockDim.x + threadIdx.x;
    const int stride = gridDim.x * blockDim.x;
    for (int i = gid; i < NX + NW; i += stride) {
        const int4* s; int4* d; int j;
        if (i < NX) { s = xs; d = xp; j = i; }
        else        { s = ws; d = wp; j = i - NX; }
        int4 a = s[4 * j + 0];
        int4 b = s[4 * j + 1];
        int4 c = s[4 * j + 2];
        int4 e = s[4 * j + 3];
        int4 o;
        o.x = (int)((a.x & 0xffu) | ((a.y & 0xffu) << 8) | ((a.z & 0xffu) << 16) | ((a.w & 0xffu) << 24));
        o.y = (int)((b.x & 0xffu) | ((b.y & 0xffu) << 8) | ((b.z & 0xffu) << 16) | ((b.w & 0xffu) << 24));
        o.z = (int)((c.x & 0xffu) | ((c.y & 0xffu) << 8) | ((c.z & 0xffu) << 16) | ((c.w & 0xffu) << 24));
        o.w = (int)((e.x & 0xffu) | ((e.y & 0xffu) << 8) | ((e.z & 0xffu) << 16) | ((e.w & 0xffu) << 24));
        d[j] = o;
    }
    if (gid < OUT_F) out_tail[gid] = bias[gid];
}

// ---- int8 GEMM: 256x256 tile, BK=64B, frag-linear LDS, 4-buf ring, vmcnt(8) ----
__global__ __launch_bounds__(512, 2) void gemm_i8_kernel(
    const char* __restrict__ A,      // packed x  [TOKENS][IN_F] int8
    const char* __restrict__ B,      // packed w  [OUT_F][IN_F] int8 (B^T layout)
    const float* __restrict__ scale, // [OUT_F]
    const float* __restrict__ bias,  // [OUT_F]
    float* __restrict__ out)         // [TOKENS][OUT_F] fp16-valued fp32
{
    __shared__ char lds[4 * BUFSZ];  // 128 KiB

    const int tid  = threadIdx.x;
    const int wid  = tid >> 6;
    const int lane = tid & 63;
    const int wm   = wid >> 2;   // 0..1  -> M offset wm*128 (8 frags)
    const int wn   = wid & 3;    // 0..3  -> N offset wn*64  (4 frags)

    // XCD rect swizzle: 16 rects (4 tm-blocks x 4 tn-blocks) of 8tm x 4tn.
    const int bid   = blockIdx.x;
    const int xcd   = bid & 7;
    const int j9    = bid >> 3;          // 0..63
    const int rect  = (j9 >> 5) * 8 + xcd;
    const int jj    = j9 & 31;
    const int tm    = (rect & 3) * 8 + (jj & 7);    // 0..31
    const int tn    = (rect >> 2) * 4 + (jj >> 3);  // 0..15

    const char* ag = A + (size_t)(tm * 256) * IN_F;
    const char* bg = B + (size_t)(tn * 256) * IN_F;

    // Frag-linear LDS layout: region byte L = frag*1024 + l*16 holds
    // G[frag*16 + (l&15)][kstep*64 + (l>>4)*16]  (exactly the MFMA operand order).
    // Staging: thread tid writes L = i*8192 + tid*16 (LINEAR dest) -> source:
    //   frag = i*8 + (tid>>6), row16 = tid&15, kg = (tid>>4)&3.
    const size_t gsub = (size_t)((tid >> 6) * 16 + (tid & 15)) * IN_F + (((tid >> 4) & 3) << 4);
    const int    ldst = tid * 16;

#define STAGE(r, t)                                                                        \
    do {                                                                                   \
        _Pragma("unroll")                                                                  \
        for (int i = 0; i < 2; ++i) {                                                      \
            size_t go = (size_t)(i * 128) * IN_F + gsub + (size_t)(t) * 64;                \
            __builtin_amdgcn_global_load_lds(                                              \
                (const __attribute__((address_space(1))) void*)(ag + go),                  \
                (__attribute__((address_space(3))) void*)(&lds[(r) * BUFSZ +               \
                                                              i * 8192 + ldst]),           \
                16, 0, 0);                                                                 \
            __builtin_amdgcn_global_load_lds(                                              \
                (const __attribute__((address_space(1))) void*)(bg + go),                  \
                (__attribute__((address_space(3))) void*)(&lds[(r) * BUFSZ + REG +         \
                                                              i * 8192 + ldst]),           \
                16, 0, 0);                                                                 \
        }                                                                                  \
    } while (0)

    // Fragment reads: contiguous 1 KB per frag, lane-linear => conflict-free.
    const int aoff = wm * 8 * 1024 + lane * 16;          // + m*1024
    const int boff = REG + wn * 4 * 1024 + lane * 16;    // + n*1024

    i32x4 acc[8][4];
#pragma unroll
    for (int m = 0; m < 8; ++m)
#pragma unroll
        for (int n = 0; n < 4; ++n)
            acc[m][n] = (i32x4){0, 0, 0, 0};

    // Prologue: 3 K-steps in flight (12 loads).
    STAGE(0, 0);
    STAGE(1, 1);
    STAGE(2, 2);

#define TILE(t, VM, DOSTAGE)                                                               \
    do {                                                                                   \
        asm volatile("s_waitcnt vmcnt(" #VM ")" ::: "memory");                             \
        __builtin_amdgcn_s_barrier();                                                      \
        __builtin_amdgcn_sched_barrier(0);                                                 \
        const char* Lr = &lds[((t) & 3) * BUFSZ];                                          \
        i32x4 af[8], bf[4];                                                                \
        _Pragma("unroll")                                                                  \
        for (int n = 0; n < 4; ++n)                                                        \
            bf[n] = *(const i32x4*)(Lr + boff + n * 1024);                                 \
        _Pragma("unroll")                                                                  \
        for (int m = 0; m < 8; ++m)                                                        \
            af[m] = *(const i32x4*)(Lr + aoff + m * 1024);                                 \
        if (DOSTAGE) STAGE(((t) + 3) & 3, (t) + 3);                                        \
        __builtin_amdgcn_s_setprio(1);                                                     \
        _Pragma("unroll")                                                                  \
        for (int m = 0; m < 8; ++m)                                                        \
            _Pragma("unroll")                                                              \
            for (int n = 0; n < 4; ++n)                                                    \
                acc[m][n] = __builtin_amdgcn_mfma_i32_16x16x64_i8(                         \
                    af[m], bf[n], acc[m][n], 0, 0, 0);                                     \
        __builtin_amdgcn_s_setprio(0);                                                     \
    } while (0)

#pragma unroll 1
    for (int t = 0; t <= NK64 - 4; ++t) TILE(t, 8, 1);
    TILE(NK64 - 3, 8, 0);
    TILE(NK64 - 2, 4, 0);
    TILE(NK64 - 1, 0, 0);

    // ---------------- epilogue: dequant + bias, fp16 round, store fp32 ----------------
    const int col  = tn * 256 + wn * 64 + (lane & 15);
    const int row0 = tm * 256 + wm * 128 + ((lane >> 4) << 2);
    float sc[4], bi[4];
#pragma unroll
    for (int n = 0; n < 4; ++n) {
        sc[n] = scale[col + n * 16];
        bi[n] = bias[col + n * 16];
    }
#pragma unroll
    for (int m = 0; m < 8; ++m)
#pragma unroll
        for (int n = 0; n < 4; ++n)
#pragma unroll
            for (int r = 0; r < 4; ++r) {
                float v = (float)acc[m][n][r] * sc[n] + bi[n];
                out[(size_t)(row0 + m * 16 + r) * OUT_F + col + n * 16] =
                    (float)__float2half_rn(v);
            }
#undef STAGE
#undef TILE
}

extern "C" void kernel_launch(void* const* d_in, const int* in_sizes, int n_in,
                              void* d_out, int out_size, void* d_ws, size_t ws_size,
                              hipStream_t stream) {
    const int*   x_i32 = (const int*)d_in[0];
    const int*   w_i32 = (const int*)d_in[1];
    const float* scale = (const float*)d_in[2];
    const float* bias  = (const float*)d_in[3];
    float*       out   = (float*)d_out;

    char* xp = (char*)d_ws;                   // 32 MB packed x
    char* wp = xp + (size_t)TOKENS * IN_F;    // 16 MB packed weight

    prep_kernel<<<3072, 256, 0, stream>>>((const int4*)x_i32, (const int4*)w_i32, bias,
                                          (int4*)xp, (int4*)wp, out + (size_t)TOKENS * OUT_F);

    gemm_i8_kernel<<<(TOKENS / 256) * (OUT_F / 256), 512, 0, stream>>>(xp, wp, scale, bias, out);
}

// Round 7
// 183.933 us; speedup vs baseline: 1.1093x; 1.1093x over previous
//
#include <hip/hip_runtime.h>
#include <hip/hip_fp16.h>

#define TOKENS 8192
#define IN_F   4096
#define OUT_F  4096
#define NK64   (IN_F / 64)   // 64 K-steps of 64 bytes

#define REG    16384         // one matrix region: 16 frags x 1 KB (frag-linear layout)
#define BUFSZ  (2 * REG)     // A + B = 32 KiB per ring buffer
typedef __attribute__((ext_vector_type(4))) int i32x4;

// ---- prep: pack int32->int8 AND permute into MFMA-tile order + bias echo ----
// Output layout (per matrix): block b = tile*64 + kstep (16 KB each);
//   byte addr = b*16384 + frag*1024 + lane*16 + j
//   content   = M[tile*256 + frag*16 + (lane&15)][kstep*64 + (lane>>4)*16 + j]
// This is exactly the LDS image the GEMM stages, so GEMM staging is linear.
__global__ void prep_kernel(const int* __restrict__ xs, const int* __restrict__ ws,
                            const float* __restrict__ bias,
                            int4* __restrict__ xp, int4* __restrict__ wp,
                            float* __restrict__ out_tail) {
    const int NA = (TOKENS / 256) * 64 * 1024;   // 2,097,152 16-B slots
    const int NB = (OUT_F  / 256) * 64 * 1024;   // 1,048,576 16-B slots
    const int gid = blockIdx.x * blockDim.x + threadIdx.x;
    const int stride = gridDim.x * blockDim.x;
    for (int s = gid; s < NA + NB; s += stride) {
        const int* src; int4* dst; int t2;
        if (s < NA) { src = xs; dst = xp; t2 = s; }
        else        { src = ws; dst = wp; t2 = s - NA; }
        const int slot = t2 & 1023;           // slot within 16-KB block
        const int blk  = t2 >> 10;            // tile*64 + kstep
        const int f    = slot >> 6;
        const int l    = slot & 63;
        const int row  = (blk >> 6) * 256 + f * 16 + (l & 15);
        const int k0   = (blk & 63) * 64 + ((l >> 4) << 4);
        const int* p   = src + (size_t)row * IN_F + k0;
        int4 a = *(const int4*)(p + 0);
        int4 b = *(const int4*)(p + 4);
        int4 c = *(const int4*)(p + 8);
        int4 e = *(const int4*)(p + 12);
        int4 o;
        o.x = (int)((a.x & 0xffu) | ((a.y & 0xffu) << 8) | ((a.z & 0xffu) << 16) | ((a.w & 0xffu) << 24));
        o.y = (int)((b.x & 0xffu) | ((b.y & 0xffu) << 8) | ((b.z & 0xffu) << 16) | ((b.w & 0xffu) << 24));
        o.z = (int)((c.x & 0xffu) | ((c.y & 0xffu) << 8) | ((c.z & 0xffu) << 16) | ((c.w & 0xffu) << 24));
        o.w = (int)((e.x & 0xffu) | ((e.y & 0xffu) << 8) | ((e.z & 0xffu) << 16) | ((e.w & 0xffu) << 24));
        dst[t2] = o;
    }
    if (gid < OUT_F) out_tail[gid] = bias[gid];
}

// ---- int8 GEMM: 256x256 tile, BK=64B, pre-permuted linear staging, frag-linear LDS,
// ----            4-buf ring, head-of-step vmcnt(8), 1 barrier/step ----
__global__ __launch_bounds__(512, 2) void gemm_i8_kernel(
    const char* __restrict__ A,      // permuted x tiles: [32][64] blocks of 16 KB
    const char* __restrict__ B,      // permuted w tiles: [16][64] blocks of 16 KB
    const float* __restrict__ scale, // [OUT_F]
    const float* __restrict__ bias,  // [OUT_F]
    float* __restrict__ out)         // [TOKENS][OUT_F] fp16-valued fp32
{
    __shared__ char lds[4 * BUFSZ];  // 128 KiB

    const int tid  = threadIdx.x;
    const int wid  = tid >> 6;
    const int lane = tid & 63;
    const int wm   = wid >> 2;   // 0..1  -> M offset wm*128 (8 frags)
    const int wn   = wid & 3;    // 0..3  -> N offset wn*64  (4 frags)

    // XCD rect swizzle: 16 rects (4 tm-blocks x 4 tn-blocks) of 8tm x 4tn.
    const int bid   = blockIdx.x;
    const int xcd   = bid & 7;
    const int j9    = bid >> 3;          // 0..63
    const int rect  = (j9 >> 5) * 8 + xcd;
    const int jj    = j9 & 31;
    const int tm    = (rect & 3) * 8 + (jj & 7);    // 0..31
    const int tn    = (rect >> 2) * 4 + (jj >> 3);  // 0..15

    const char* ag = A + (size_t)tm * (64 * 16384);
    const char* bg = B + (size_t)tn * (64 * 16384);
    const int   ldst = tid * 16;

#define STAGE(r, t)                                                                        \
    do {                                                                                   \
        _Pragma("unroll")                                                                  \
        for (int i = 0; i < 2; ++i) {                                                      \
            size_t go = (size_t)(t) * 16384 + i * 8192 + ldst;                             \
            __builtin_amdgcn_global_load_lds(                                              \
                (const __attribute__((address_space(1))) void*)(ag + go),                  \
                (__attribute__((address_space(3))) void*)(&lds[(r) * BUFSZ +               \
                                                              i * 8192 + ldst]),           \
                16, 0, 0);                                                                 \
            __builtin_amdgcn_global_load_lds(                                              \
                (const __attribute__((address_space(1))) void*)(bg + go),                  \
                (__attribute__((address_space(3))) void*)(&lds[(r) * BUFSZ + REG +         \
                                                              i * 8192 + ldst]),           \
                16, 0, 0);                                                                 \
        }                                                                                  \
    } while (0)

    // Fragment reads: contiguous 1 KB per frag, lane-linear => conflict-free.
    const int aoff = wm * 8 * 1024 + lane * 16;          // + m*1024
    const int boff = REG + wn * 4 * 1024 + lane * 16;    // + n*1024

    i32x4 acc[8][4];
#pragma unroll
    for (int m = 0; m < 8; ++m)
#pragma unroll
        for (int n = 0; n < 4; ++n)
            acc[m][n] = (i32x4){0, 0, 0, 0};

    // Prologue: 3 K-steps in flight (12 loads).
    STAGE(0, 0);
    STAGE(1, 1);
    STAGE(2, 2);

#define TILE(t, VM, DOSTAGE)                                                               \
    do {                                                                                   \
        asm volatile("s_waitcnt vmcnt(" #VM ")" ::: "memory");                             \
        __builtin_amdgcn_s_barrier();                                                      \
        __builtin_amdgcn_sched_barrier(0);                                                 \
        const char* Lr = &lds[((t) & 3) * BUFSZ];                                          \
        i32x4 af[8], bf[4];                                                                \
        _Pragma("unroll")                                                                  \
        for (int n = 0; n < 4; ++n)                                                        \
            bf[n] = *(const i32x4*)(Lr + boff + n * 1024);                                 \
        _Pragma("unroll")                                                                  \
        for (int m = 0; m < 8; ++m)                                                        \
            af[m] = *(const i32x4*)(Lr + aoff + m * 1024);                                 \
        if (DOSTAGE) STAGE(((t) + 3) & 3, (t) + 3);                                        \
        __builtin_amdgcn_s_setprio(1);                                                     \
        _Pragma("unroll")                                                                  \
        for (int m = 0; m < 8; ++m)                                                        \
            _Pragma("unroll")                                                              \
            for (int n = 0; n < 4; ++n)                                                    \
                acc[m][n] = __builtin_amdgcn_mfma_i32_16x16x64_i8(                         \
                    af[m], bf[n], acc[m][n], 0, 0, 0);                                     \
        __builtin_amdgcn_s_setprio(0);                                                     \
    } while (0)

#pragma unroll 1
    for (int t = 0; t <= NK64 - 4; ++t) TILE(t, 8, 1);
    TILE(NK64 - 3, 8, 0);
    TILE(NK64 - 2, 4, 0);
    TILE(NK64 - 1, 0, 0);

    // ---------------- epilogue: dequant + bias, fp16 round, store fp32 ----------------
    const int col  = tn * 256 + wn * 64 + (lane & 15);
    const int row0 = tm * 256 + wm * 128 + ((lane >> 4) << 2);
    float sc[4], bi[4];
#pragma unroll
    for (int n = 0; n < 4; ++n) {
        sc[n] = scale[col + n * 16];
        bi[n] = bias[col + n * 16];
    }
#pragma unroll
    for (int m = 0; m < 8; ++m)
#pragma unroll
        for (int n = 0; n < 4; ++n)
#pragma unroll
            for (int r = 0; r < 4; ++r) {
                float v = (float)acc[m][n][r] * sc[n] + bi[n];
                out[(size_t)(row0 + m * 16 + r) * OUT_F + col + n * 16] =
                    (float)__float2half_rn(v);
            }
#undef STAGE
#undef TILE
}

extern "C" void kernel_launch(void* const* d_in, const int* in_sizes, int n_in,
                              void* d_out, int out_size, void* d_ws, size_t ws_size,
                              hipStream_t stream) {
    const int*   x_i32 = (const int*)d_in[0];
    const int*   w_i32 = (const int*)d_in[1];
    const float* scale = (const float*)d_in[2];
    const float* bias  = (const float*)d_in[3];
    float*       out   = (float*)d_out;

    char* xp = (char*)d_ws;                   // 32 MB permuted x
    char* wp = xp + (size_t)TOKENS * IN_F;    // 16 MB permuted weight

    prep_kernel<<<3072, 256, 0, stream>>>(x_i32, w_i32, bias,
                                          (int4*)xp, (int4*)wp, out + (size_t)TOKENS * OUT_F);

    gemm_i8_kernel<<<(TOKENS / 256) * (OUT_F / 256), 512, 0, stream>>>(xp, wp, scale, bias, out);
}